// Round 9
// baseline (133.654 us; speedup 1.0000x reference)
//
#include <hip/hip_runtime.h>
#include <hip/hip_fp16.h>
#include <math.h>

#define DEV __device__ __forceinline__

// Soft gate: c0 + ca*a + cb*b + cab*(a*b)
DEV float gev(float4 c, float a, float b) {
    return fmaf(c.w, a * b, fmaf(c.z, b, fmaf(c.y, a, c.x)));
}

// softmax over 16 op-logits -> affine coefficients {c0, ca, cb, cab}
DEV float4 softmax_coef(const float* __restrict__ wrow) {
    const float4* wv = (const float4*)wrow;
    float4 q0 = wv[0], q1 = wv[1], q2 = wv[2], q3 = wv[3];
    float p[16] = {q0.x,q0.y,q0.z,q0.w, q1.x,q1.y,q1.z,q1.w,
                   q2.x,q2.y,q2.z,q2.w, q3.x,q3.y,q3.z,q3.w};
    float mx = p[0];
    #pragma unroll
    for (int k = 1; k < 16; k++) mx = fmaxf(mx, p[k]);
    float s = 0.f;
    #pragma unroll
    for (int k = 0; k < 16; k++) { p[k] = __expf(p[k] - mx); s += p[k]; }
    float inv = 1.f / s;
    #pragma unroll
    for (int k = 0; k < 16; k++) p[k] *= inv;
    float c0  = p[8]+p[9]+p[10]+p[11]+p[12]+p[13]+p[14]+p[15];
    float ca  = p[2]+p[3]+p[6]+p[7]-p[8]-p[9]-p[12]-p[13];
    float cb  = p[4]+p[5]+p[6]+p[7]-p[8]-p[9]-p[10]-p[11];
    float cab = p[1]-p[2]-p[4]-2.f*p[6]-p[7]+p[8]+2.f*p[9]+p[11]+p[13]-p[14];
    return make_float4(c0, ca, cb, cab);
}

DEV float4 onehot4(int i) {
    return make_float4(i == 0 ? 1.f : 0.f, i == 1 ? 1.f : 0.f,
                       i == 2 ? 1.f : 0.f, i == 3 ? 1.f : 0.f);
}

// ---------------------------------------------------------------------------
// LDS pitches (de-harmonized vs 32 banks to kill structured conflicts):
//   XB : 28 rows x pitch 29 (row stride 29; pool-row stride 58 % 32 = 26)
//   P1 : 16 planes x (14 rows x pitch 15) = 210/plane (pool-row stride 30)
//   P2 : 48 planes x (8 rows x pitch 9)  = 72/plane  (pool-row stride 18)
//   P3 : plain [144*9]
// ---------------------------------------------------------------------------

// setup_kernel: packs network into records.
//   [0,20480) fc1 | [20480,30720) fc2 | [30720,35840) fc3 : 32B {coef4|ia,ib}
//   [35840,36048): conv filter 224B (pre-decoded LDS offsets with the padded
//   pitches above, coef float4s, one-hot selector float4s)
__global__ __launch_bounds__(256) void setup_kernel(
    const int* __restrict__ c1i0, const int* __restrict__ c1i1, const int* __restrict__ c1i2,
    const int* __restrict__ c2i0, const int* __restrict__ c2i1, const int* __restrict__ c2i2,
    const int* __restrict__ c3i0, const int* __restrict__ c3i1, const int* __restrict__ c3i2,
    const float* __restrict__ c1w0, const float* __restrict__ c1w1, const float* __restrict__ c1w2,
    const float* __restrict__ c2w0, const float* __restrict__ c2w1, const float* __restrict__ c2w2,
    const float* __restrict__ c3w0, const float* __restrict__ c3w1, const float* __restrict__ c3w2,
    const int* __restrict__ fc1i, const float* __restrict__ fc1w,
    const int* __restrict__ fc2i, const float* __restrict__ fc2w,
    const int* __restrict__ fc3i, const float* __restrict__ fc3w,
    float4* __restrict__ fcp1, float4* __restrict__ fcp2, float4* __restrict__ fcp3,
    float4* __restrict__ cvp)
{
    int t = blockIdx.x * 256 + threadIdx.x;
    if (t >= 36048) return;
    if (t < 35840) {
        const float* w; const int* idx; float4* dst; int o, D;
        if (t < 20480)      { o = t;         D = 20480; w = fc1w; idx = fc1i; dst = fcp1; }
        else if (t < 30720) { o = t - 20480; D = 10240; w = fc2w; idx = fc2i; dst = fcp2; }
        else                { o = t - 30720; D = 5120;  w = fc3w; idx = fc3i; dst = fcp3; }
        dst[2 * o] = softmax_coef(w + o * 16);
        ((int4*)dst)[2 * o + 1] = make_int4(idx[o], idx[D + o], 0, 0);
        return;
    }
    int f = t - 35840;               // 0..207
    const int *i0, *i1, *i2; const float *W0, *W1, *W2;
    int F, KS, mode, lf;
    if (f < 16)      { lf = f;      F = 16;  KS = 5; mode = 1;
                       i0 = c1i0; i1 = c1i1; i2 = c1i2; W0 = c1w0; W1 = c1w1; W2 = c1w2; }
    else if (f < 64) { lf = f - 16; F = 48;  KS = 3; mode = 2;
                       i0 = c2i0; i1 = c2i1; i2 = c2i2; W0 = c2w0; W1 = c2w1; W2 = c2w2; }
    else             { lf = f - 64; F = 144; KS = 3; mode = 3;
                       i0 = c3i0; i1 = c3i1; i2 = c3i2; W0 = c3w0; W1 = c3w1; W2 = c3w2; }
    float4* pk = cvp + f * 14;
    int offs[8];
    #pragma unroll
    for (int g = 0; g < 8; g++) {
        int tt = (g < 4) ? i0[lf * 4 + g] : i0[F * 4 + lf * 4 + (g - 4)];
        int kk = KS * KS;
        int c = tt / kk, r = tt - c * kk;
        int dy = r / KS, dx = r - dy * KS;
        int off;
        if (mode == 1)      off = dy * 29 + dx;              // XB pitch 29
        else if (mode == 2) off = c * 210 + dy * 15 + dx;    // P1 plane 210, pitch 15
        else                off = c * 72 + dy * 9 + dx;      // P2 plane 72, pitch 9
        offs[g] = off;
    }
    ((int4*)pk)[0] = make_int4(offs[0], offs[1], offs[2], offs[3]);
    ((int4*)pk)[1] = make_int4(offs[4], offs[5], offs[6], offs[7]);
    #pragma unroll
    for (int g = 0; g < 4; g++) pk[2 + g] = softmax_coef(W0 + (lf * 4 + g) * 16);
    pk[6] = onehot4(i1[lf * 2 + 0]);
    pk[7] = onehot4(i1[F * 2 + lf * 2 + 0]);
    pk[8] = onehot4(i1[lf * 2 + 1]);
    pk[9] = onehot4(i1[F * 2 + lf * 2 + 1]);
    pk[10] = softmax_coef(W1 + (lf * 2 + 0) * 16);
    pk[11] = softmax_coef(W1 + (lf * 2 + 1) * 16);
    int a2 = i2[lf], b2 = i2[F + lf];
    pk[12] = make_float4(a2 == 0 ? 1.f : 0.f, a2 == 1 ? 1.f : 0.f,
                         b2 == 0 ? 1.f : 0.f, b2 == 1 ? 1.f : 0.f);
    pk[13] = softmax_coef(W2 + lf * 16);
}

// ---------------------------------------------------------------------------
// Conv stage, ds_read2-friendly (per input offset one base pointer with
// offsets {0,1,PITCH,PITCH+1}).  Output: padded plane (OPLANE/OPITCH) or
// plain when OPITCH==0.
// ---------------------------------------------------------------------------
template <int PITCH, int HP, int F, int OPLANE, int OPITCH>
DEV void conv_stage(const float* Sin, float* Sout, const float4* __restrict__ pack,
                    int tid)
{
    constexpr int N = F * HP * HP;
    for (int t = tid; t < N; t += 1024) {
        int f  = t / (HP * HP);
        int p  = t - f * (HP * HP);
        int ph = p / HP, pw = p - ph * HP;
        const float4* pk = pack + f * 14;
        int4 ao = ((const int4*)pk)[0];
        int4 bo = ((const int4*)pk)[1];
        int base0 = 2 * ph * PITCH + 2 * pw;
        int offs[8] = {ao.x, ao.y, ao.z, ao.w, bo.x, bo.y, bo.z, bo.w};
        float v[8][4];
        #pragma unroll
        for (int g = 0; g < 8; g++) {
            const float* q = Sin + offs[g] + base0;
            v[g][0] = q[0];
            v[g][1] = q[1];
            v[g][2] = q[PITCH];
            v[g][3] = q[PITCH + 1];
        }
        float4 C00 = pk[2], C01 = pk[3], C02 = pk[4], C03 = pk[5];
        float4 oA0 = pk[6], oB0 = pk[7], oA1 = pk[8], oB1 = pk[9];
        float4 C10 = pk[10], C11 = pk[11], S2 = pk[12], C2 = pk[13];
        float m = -1e30f;
        #pragma unroll
        for (int q = 0; q < 4; q++) {
            float h00 = gev(C00, v[0][q], v[4][q]);
            float h01 = gev(C01, v[1][q], v[5][q]);
            float h02 = gev(C02, v[2][q], v[6][q]);
            float h03 = gev(C03, v[3][q], v[7][q]);
            float sa0 = fmaf(oA0.x, h00, fmaf(oA0.y, h01, fmaf(oA0.z, h02, oA0.w * h03)));
            float sb0 = fmaf(oB0.x, h00, fmaf(oB0.y, h01, fmaf(oB0.z, h02, oB0.w * h03)));
            float sa1 = fmaf(oA1.x, h00, fmaf(oA1.y, h01, fmaf(oA1.z, h02, oA1.w * h03)));
            float sb1 = fmaf(oB1.x, h00, fmaf(oB1.y, h01, fmaf(oB1.z, h02, oB1.w * h03)));
            float h10 = gev(C10, sa0, sb0);
            float h11 = gev(C11, sa1, sb1);
            float vv = gev(C2, fmaf(S2.x, h10, S2.y * h11),
                               fmaf(S2.z, h10, S2.w * h11));
            m = fmaxf(m, vv);
        }
        if (OPITCH)
            Sout[f * OPLANE + (ph + 1) * OPITCH + (pw + 1)] = m;
        else
            Sout[t] = m;
    }
}

// ---------------------------------------------------------------------------
// FC stage, chunk-of-CH pipeline.  DOUT % (1024*CH) == 0.
// ---------------------------------------------------------------------------
template <int DOUT, int CH, typename TIN, typename TOUT>
DEV void fc_stage(const TIN* Sin, TOUT* Sout, const float4* __restrict__ pk, int tid)
{
    constexpr int K = DOUT / 1024;
    #pragma unroll 1
    for (int k0 = 0; k0 < K; k0 += CH) {
        float4 c[CH]; int ia[CH], ib[CH];
        #pragma unroll
        for (int j = 0; j < CH; j++) {
            int o = tid + (k0 + j) * 1024;
            c[j] = pk[2 * o];
            int4 ii = ((const int4*)pk)[2 * o + 1];
            ia[j] = ii.x; ib[j] = ii.y;
        }
        float va[CH], vb[CH];
        #pragma unroll
        for (int j = 0; j < CH; j++) {
            va[j] = (float)Sin[ia[j]];
            vb[j] = (float)Sin[ib[j]];
        }
        #pragma unroll
        for (int j = 0; j < CH; j++) {
            int o = tid + (k0 + j) * 1024;
            Sout[o] = (TOUT)gev(c[j], va[j], vb[j]);
        }
    }
}

// ---------------------------------------------------------------------------
// Whole network, one WG per batch element, 1024 threads.  Aliased LDS
// (61440 B total):
//   F1h fp16 [0,40960)        | F2h fp16 [40960,61440)
//   lower (dead before fc1):  XB f32 [0,3248) | P1p f32 [3248,16688)
//   upper (dead before fc2):  P2p f32 [40960,54784) | P3 f32 [54784,59968)
//   F3 f32 [0,20480)          (aliases F1h; F1h dead after fc2)
// fc1 reads P3 (upper) while writing F1h (lower) -> no overlap.
// ---------------------------------------------------------------------------
__global__ __launch_bounds__(1024, 4) void fused_net(
    const float* __restrict__ x,
    const float4* __restrict__ fcp1, const float4* __restrict__ fcp2,
    const float4* __restrict__ fcp3, const float4* __restrict__ cvp,
    float* __restrict__ out)
{
    __shared__ __align__(16) char S[61440];
    __half* F1h = (__half*)S;
    __half* F2h = (__half*)(S + 40960);
    float*  XB  = (float*)S;                // 28 x 29 = 812
    float*  P1p = (float*)(S + 3248);       // 16 x 210 = 3360
    float*  P2p = (float*)(S + 40960);      // 48 x 72 = 3456
    float*  P3  = (float*)(S + 54784);      // 1296
    float*  F3  = (float*)S;                // 5120

    const int b = blockIdx.x, tid = threadIdx.x;
    // stage 0: binarize input into pitch-29 XB; zero padded conv buffers
    if (tid < 784) {
        int y = tid / 28, xx = tid - y * 28;
        XB[y * 29 + xx] = x[b * 784 + tid] > 0.5f ? 1.f : 0.f;
    }
    if (tid < 840) ((float4*)P1p)[tid] = make_float4(0.f, 0.f, 0.f, 0.f);
    if (tid < 864) ((float4*)P2p)[tid] = make_float4(0.f, 0.f, 0.f, 0.f);
    __syncthreads();

    conv_stage<29, 12, 16, 210, 15>(XB, P1p, cvp + 0 * 14, tid);  // c1 -> P1 padded
    __syncthreads();
    conv_stage<15, 6, 48, 72, 9>(P1p, P2p, cvp + 16 * 14, tid);   // c2 -> P2 padded
    __syncthreads();
    conv_stage<9, 3, 144, 0, 0>(P2p, P3, cvp + 64 * 14, tid);     // c3 -> P3 plain
    __syncthreads();

    fc_stage<20480, 10, float, __half>(P3, F1h, fcp1, tid);
    __syncthreads();
    fc_stage<10240, 10, __half, __half>(F1h, F2h, fcp2, tid);
    __syncthreads();
    fc_stage<5120, 5, __half, float>(F2h, F3, fcp3, tid);
    __syncthreads();

    // GroupSum: waves 0..9 each reduce one group of 512 -> out[b*10+g]
    int wave = tid >> 6, lane = tid & 63;
    if (wave < 10) {
        const float* q = F3 + wave * 512 + lane;
        float s = 0.f;
        #pragma unroll
        for (int i = 0; i < 8; i++) s += q[i * 64];
        #pragma unroll
        for (int off = 32; off > 0; off >>= 1) s += __shfl_down(s, off, 64);
        if (lane == 0) out[b * 10 + wave] = s * (1.f / 30.f);
    }
}

extern "C" void kernel_launch(void* const* d_in, const int* in_sizes, int n_in,
                              void* d_out, int out_size, void* d_ws, size_t ws_size,
                              hipStream_t stream)
{
    const float* x     = (const float*)d_in[0];
    const int*   c1i0  = (const int*)d_in[1];  const float* c1w0 = (const float*)d_in[2];
    const int*   c1i1  = (const int*)d_in[3];  const float* c1w1 = (const float*)d_in[4];
    const int*   c1i2  = (const int*)d_in[5];  const float* c1w2 = (const float*)d_in[6];
    const int*   c2i0  = (const int*)d_in[7];  const float* c2w0 = (const float*)d_in[8];
    const int*   c2i1  = (const int*)d_in[9];  const float* c2w1 = (const float*)d_in[10];
    const int*   c2i2  = (const int*)d_in[11]; const float* c2w2 = (const float*)d_in[12];
    const int*   c3i0  = (const int*)d_in[13]; const float* c3w0 = (const float*)d_in[14];
    const int*   c3i1  = (const int*)d_in[15]; const float* c3w1 = (const float*)d_in[16];
    const int*   c3i2  = (const int*)d_in[17]; const float* c3w2 = (const float*)d_in[18];
    const int*   fc1i  = (const int*)d_in[19]; const float* fc1w = (const float*)d_in[20];
    const int*   fc2i  = (const int*)d_in[21]; const float* fc2w = (const float*)d_in[22];
    const int*   fc3i  = (const int*)d_in[23]; const float* fc3w = (const float*)d_in[24];

    // ws: fcp1 @0 (655360) | fcp2 @655360 (327680) | fcp3 @983040 (163840)
    //     | convpack @1146880 (46592)
    char* ws = (char*)d_ws;
    float4* fcp1 = (float4*)ws;
    float4* fcp2 = (float4*)(ws + 655360);
    float4* fcp3 = (float4*)(ws + 983040);
    float4* cvp  = (float4*)(ws + 1146880);

    setup_kernel<<<141, 256, 0, stream>>>(
        c1i0, c1i1, c1i2, c2i0, c2i1, c2i2, c3i0, c3i1, c3i2,
        c1w0, c1w1, c1w2, c2w0, c2w1, c2w2, c3w0, c3w1, c3w2,
        fc1i, fc1w, fc2i, fc2w, fc3i, fc3w,
        fcp1, fcp2, fcp3, cvp);

    fused_net<<<100, 1024, 0, stream>>>(
        x, fcp1, fcp2, fcp3, cvp, (float*)d_out);
}

// Round 10
// 125.604 us; speedup vs baseline: 1.0641x; 1.0641x over previous
//
#include <hip/hip_runtime.h>
#include <hip/hip_fp16.h>
#include <math.h>

#define DEV __device__ __forceinline__

// Soft gate: c0 + ca*a + cb*b + cab*(a*b)
DEV float gev(float4 c, float a, float b) {
    return fmaf(c.w, a * b, fmaf(c.z, b, fmaf(c.y, a, c.x)));
}

// 16-byte fc gate record: fp16 coefs + u16 index pair (halves L1 stream vs 32B)
struct __align__(16) FcRec {
    __half2 c01, c23;   // {c0,ca}, {cb,cab}
    unsigned int idx;   // ia | ib<<16
    unsigned int pad;
};

// softmax over 16 op-logits -> affine coefficients {c0, ca, cb, cab}
DEV float4 softmax_coef(const float* __restrict__ wrow) {
    const float4* wv = (const float4*)wrow;
    float4 q0 = wv[0], q1 = wv[1], q2 = wv[2], q3 = wv[3];
    float p[16] = {q0.x,q0.y,q0.z,q0.w, q1.x,q1.y,q1.z,q1.w,
                   q2.x,q2.y,q2.z,q2.w, q3.x,q3.y,q3.z,q3.w};
    float mx = p[0];
    #pragma unroll
    for (int k = 1; k < 16; k++) mx = fmaxf(mx, p[k]);
    float s = 0.f;
    #pragma unroll
    for (int k = 0; k < 16; k++) { p[k] = __expf(p[k] - mx); s += p[k]; }
    float inv = 1.f / s;
    #pragma unroll
    for (int k = 0; k < 16; k++) p[k] *= inv;
    float c0  = p[8]+p[9]+p[10]+p[11]+p[12]+p[13]+p[14]+p[15];
    float ca  = p[2]+p[3]+p[6]+p[7]-p[8]-p[9]-p[12]-p[13];
    float cb  = p[4]+p[5]+p[6]+p[7]-p[8]-p[9]-p[10]-p[11];
    float cab = p[1]-p[2]-p[4]-2.f*p[6]-p[7]+p[8]+2.f*p[9]+p[11]+p[13]-p[14];
    return make_float4(c0, ca, cb, cab);
}

DEV float4 onehot4(int i) {
    return make_float4(i == 0 ? 1.f : 0.f, i == 1 ? 1.f : 0.f,
                       i == 2 ? 1.f : 0.f, i == 3 ? 1.f : 0.f);
}

// ---------------------------------------------------------------------------
// setup_kernel: packs network.
//   [0,20480) fc1 | [20480,30720) fc2 | [30720,35840) fc3 : 16B FcRec
//   [35840,36048): conv filter 224B f32 records (R8 layout: pre-decoded LDS
//   offsets for XB 28x28 / P1 16x14x14 / P2 48x8x8, coef + one-hot float4s)
// ---------------------------------------------------------------------------
__global__ __launch_bounds__(256) void setup_kernel(
    const int* __restrict__ c1i0, const int* __restrict__ c1i1, const int* __restrict__ c1i2,
    const int* __restrict__ c2i0, const int* __restrict__ c2i1, const int* __restrict__ c2i2,
    const int* __restrict__ c3i0, const int* __restrict__ c3i1, const int* __restrict__ c3i2,
    const float* __restrict__ c1w0, const float* __restrict__ c1w1, const float* __restrict__ c1w2,
    const float* __restrict__ c2w0, const float* __restrict__ c2w1, const float* __restrict__ c2w2,
    const float* __restrict__ c3w0, const float* __restrict__ c3w1, const float* __restrict__ c3w2,
    const int* __restrict__ fc1i, const float* __restrict__ fc1w,
    const int* __restrict__ fc2i, const float* __restrict__ fc2w,
    const int* __restrict__ fc3i, const float* __restrict__ fc3w,
    FcRec* __restrict__ fcp1, FcRec* __restrict__ fcp2, FcRec* __restrict__ fcp3,
    float4* __restrict__ cvp)
{
    int t = blockIdx.x * 256 + threadIdx.x;
    if (t >= 36048) return;
    if (t < 35840) {
        const float* w; const int* idx; FcRec* dst; int o, D;
        if (t < 20480)      { o = t;         D = 20480; w = fc1w; idx = fc1i; dst = fcp1; }
        else if (t < 30720) { o = t - 20480; D = 10240; w = fc2w; idx = fc2i; dst = fcp2; }
        else                { o = t - 30720; D = 5120;  w = fc3w; idx = fc3i; dst = fcp3; }
        float4 cf = softmax_coef(w + o * 16);
        FcRec r;
        r.c01 = __half2(__float2half_rn(cf.x), __float2half_rn(cf.y));
        r.c23 = __half2(__float2half_rn(cf.z), __float2half_rn(cf.w));
        r.idx = ((unsigned)idx[o] & 0xffffu) | ((unsigned)idx[D + o] << 16);
        r.pad = 0;
        dst[o] = r;
        return;
    }
    int f = t - 35840;               // 0..207
    const int *i0, *i1, *i2; const float *W0, *W1, *W2;
    int F, KS, mode, lf;
    if (f < 16)      { lf = f;      F = 16;  KS = 5; mode = 1;
                       i0 = c1i0; i1 = c1i1; i2 = c1i2; W0 = c1w0; W1 = c1w1; W2 = c1w2; }
    else if (f < 64) { lf = f - 16; F = 48;  KS = 3; mode = 2;
                       i0 = c2i0; i1 = c2i1; i2 = c2i2; W0 = c2w0; W1 = c2w1; W2 = c2w2; }
    else             { lf = f - 64; F = 144; KS = 3; mode = 3;
                       i0 = c3i0; i1 = c3i1; i2 = c3i2; W0 = c3w0; W1 = c3w1; W2 = c3w2; }
    float4* pk = cvp + f * 14;
    int offs[8];
    #pragma unroll
    for (int g = 0; g < 8; g++) {
        int tt = (g < 4) ? i0[lf * 4 + g] : i0[F * 4 + lf * 4 + (g - 4)];
        int kk = KS * KS;
        int c = tt / kk, r = tt - c * kk;
        int dy = r / KS, dx = r - dy * KS;
        int off;
        if (mode == 1)      off = dy * 28 + dx;              // XB 28x28
        else if (mode == 2) off = (c * 14 + dy) * 14 + dx;   // P1 16x14x14 padded
        else                off = (c * 8 + dy) * 8 + dx;     // P2 48x8x8 padded
        offs[g] = off;
    }
    ((int4*)pk)[0] = make_int4(offs[0], offs[1], offs[2], offs[3]);
    ((int4*)pk)[1] = make_int4(offs[4], offs[5], offs[6], offs[7]);
    #pragma unroll
    for (int g = 0; g < 4; g++) pk[2 + g] = softmax_coef(W0 + (lf * 4 + g) * 16);
    pk[6] = onehot4(i1[lf * 2 + 0]);
    pk[7] = onehot4(i1[F * 2 + lf * 2 + 0]);
    pk[8] = onehot4(i1[lf * 2 + 1]);
    pk[9] = onehot4(i1[F * 2 + lf * 2 + 1]);
    pk[10] = softmax_coef(W1 + (lf * 2 + 0) * 16);
    pk[11] = softmax_coef(W1 + (lf * 2 + 1) * 16);
    int a2 = i2[lf], b2 = i2[F + lf];
    pk[12] = make_float4(a2 == 0 ? 1.f : 0.f, a2 == 1 ? 1.f : 0.f,
                         b2 == 0 ? 1.f : 0.f, b2 == 1 ? 1.f : 0.f);
    pk[13] = softmax_coef(W2 + lf * 16);
}

// ---------------------------------------------------------------------------
// Conv stage (R8-measured-best): ds_read2-friendly — per input offset one
// base pointer with offsets {0,1,PITCH,PITCH+1}.
// ---------------------------------------------------------------------------
template <int PITCH, int HP, int F, int OUTP>
DEV void conv_stage(const float* Sin, float* Sout, const float4* __restrict__ pack,
                    int tid)
{
    constexpr int N = F * HP * HP;
    for (int t = tid; t < N; t += 1024) {
        int f  = t / (HP * HP);
        int p  = t - f * (HP * HP);
        int ph = p / HP, pw = p - ph * HP;
        const float4* pk = pack + f * 14;
        int4 ao = ((const int4*)pk)[0];
        int4 bo = ((const int4*)pk)[1];
        int base0 = 2 * ph * PITCH + 2 * pw;
        int offs[8] = {ao.x, ao.y, ao.z, ao.w, bo.x, bo.y, bo.z, bo.w};
        float v[8][4];
        #pragma unroll
        for (int g = 0; g < 8; g++) {
            const float* q = Sin + offs[g] + base0;
            v[g][0] = q[0];
            v[g][1] = q[1];
            v[g][2] = q[PITCH];
            v[g][3] = q[PITCH + 1];
        }
        float4 C00 = pk[2], C01 = pk[3], C02 = pk[4], C03 = pk[5];
        float4 oA0 = pk[6], oB0 = pk[7], oA1 = pk[8], oB1 = pk[9];
        float4 C10 = pk[10], C11 = pk[11], S2 = pk[12], C2 = pk[13];
        float m = -1e30f;
        #pragma unroll
        for (int q = 0; q < 4; q++) {
            float h00 = gev(C00, v[0][q], v[4][q]);
            float h01 = gev(C01, v[1][q], v[5][q]);
            float h02 = gev(C02, v[2][q], v[6][q]);
            float h03 = gev(C03, v[3][q], v[7][q]);
            float sa0 = fmaf(oA0.x, h00, fmaf(oA0.y, h01, fmaf(oA0.z, h02, oA0.w * h03)));
            float sb0 = fmaf(oB0.x, h00, fmaf(oB0.y, h01, fmaf(oB0.z, h02, oB0.w * h03)));
            float sa1 = fmaf(oA1.x, h00, fmaf(oA1.y, h01, fmaf(oA1.z, h02, oA1.w * h03)));
            float sb1 = fmaf(oB1.x, h00, fmaf(oB1.y, h01, fmaf(oB1.z, h02, oB1.w * h03)));
            float h10 = gev(C10, sa0, sb0);
            float h11 = gev(C11, sa1, sb1);
            float vv = gev(C2, fmaf(S2.x, h10, S2.y * h11),
                               fmaf(S2.z, h10, S2.w * h11));
            m = fmaxf(m, vv);
        }
        if (OUTP)
            Sout[(f * OUTP + ph + 1) * OUTP + (pw + 1)] = m;
        else
            Sout[t] = m;
    }
}

// ---------------------------------------------------------------------------
// FC stage with 16B records, chunk-of-CH pipeline.  DOUT % (1024*CH) == 0.
// ---------------------------------------------------------------------------
template <int DOUT, int CH, typename TIN, typename TOUT>
DEV void fc_stage(const TIN* Sin, TOUT* Sout, const FcRec* __restrict__ pk, int tid)
{
    constexpr int K = DOUT / 1024;
    #pragma unroll 1
    for (int k0 = 0; k0 < K; k0 += CH) {
        FcRec r[CH];
        #pragma unroll
        for (int j = 0; j < CH; j++) r[j] = pk[tid + (k0 + j) * 1024];
        float va[CH], vb[CH];
        #pragma unroll
        for (int j = 0; j < CH; j++) {
            unsigned ii = r[j].idx;
            va[j] = (float)Sin[ii & 0xffffu];
            vb[j] = (float)Sin[ii >> 16];
        }
        #pragma unroll
        for (int j = 0; j < CH; j++) {
            float2 c01 = __half22float2(r[j].c01);
            float2 c23 = __half22float2(r[j].c23);
            float4 c = make_float4(c01.x, c01.y, c23.x, c23.y);
            Sout[tid + (k0 + j) * 1024] = (TOUT)gev(c, va[j], vb[j]);
        }
    }
}

// ---------------------------------------------------------------------------
// Whole network, one WG per batch element, 1024 threads.  Aliased LDS
// (61440 B, R8-measured-best layout):
//   F1h fp16 [0,40960) | F2h fp16 [40960,61440) | P1p f32 [0,12544) |
//   XB f32 [12544,15680) | P2p f32 [40960,53248) | P3 f32 [53248,58432) |
//   F3 f32 [0,20480)
// ---------------------------------------------------------------------------
__global__ __launch_bounds__(1024, 4) void fused_net(
    const float* __restrict__ x,
    const FcRec* __restrict__ fcp1, const FcRec* __restrict__ fcp2,
    const FcRec* __restrict__ fcp3, const float4* __restrict__ cvp,
    float* __restrict__ out)
{
    __shared__ __align__(16) char S[61440];
    __half* F1h = (__half*)S;
    __half* F2h = (__half*)(S + 40960);
    float*  P1p = (float*)S;
    float*  XB  = (float*)(S + 12544);
    float*  P2p = (float*)(S + 40960);
    float*  P3  = (float*)(S + 53248);
    float*  F3  = (float*)S;

    const int b = blockIdx.x, tid = threadIdx.x;
    if (tid < 784) XB[tid] = x[b * 784 + tid] > 0.5f ? 1.f : 0.f;
    if (tid < 784) ((float4*)P1p)[tid] = make_float4(0.f, 0.f, 0.f, 0.f);
    if (tid < 768) ((float4*)P2p)[tid] = make_float4(0.f, 0.f, 0.f, 0.f);
    __syncthreads();

    conv_stage<28, 12, 16, 14>(XB, P1p, cvp + 0 * 14, tid);   // c1 -> P1 padded
    __syncthreads();
    conv_stage<14, 6, 48, 8>(P1p, P2p, cvp + 16 * 14, tid);   // c2 -> P2 padded
    __syncthreads();
    conv_stage<8, 3, 144, 0>(P2p, P3, cvp + 64 * 14, tid);    // c3 -> P3 plain
    __syncthreads();

    fc_stage<20480, 10, float, __half>(P3, F1h, fcp1, tid);
    __syncthreads();
    fc_stage<10240, 10, __half, __half>(F1h, F2h, fcp2, tid);
    __syncthreads();
    fc_stage<5120, 5, __half, float>(F2h, F3, fcp3, tid);
    __syncthreads();

    // GroupSum: waves 0..9 each reduce one group of 512 -> out[b*10+g]
    int wave = tid >> 6, lane = tid & 63;
    if (wave < 10) {
        const float* q = F3 + wave * 512 + lane;
        float s = 0.f;
        #pragma unroll
        for (int i = 0; i < 8; i++) s += q[i * 64];
        #pragma unroll
        for (int off = 32; off > 0; off >>= 1) s += __shfl_down(s, off, 64);
        if (lane == 0) out[b * 10 + wave] = s * (1.f / 30.f);
    }
}

extern "C" void kernel_launch(void* const* d_in, const int* in_sizes, int n_in,
                              void* d_out, int out_size, void* d_ws, size_t ws_size,
                              hipStream_t stream)
{
    const float* x     = (const float*)d_in[0];
    const int*   c1i0  = (const int*)d_in[1];  const float* c1w0 = (const float*)d_in[2];
    const int*   c1i1  = (const int*)d_in[3];  const float* c1w1 = (const float*)d_in[4];
    const int*   c1i2  = (const int*)d_in[5];  const float* c1w2 = (const float*)d_in[6];
    const int*   c2i0  = (const int*)d_in[7];  const float* c2w0 = (const float*)d_in[8];
    const int*   c2i1  = (const int*)d_in[9];  const float* c2w1 = (const float*)d_in[10];
    const int*   c2i2  = (const int*)d_in[11]; const float* c2w2 = (const float*)d_in[12];
    const int*   c3i0  = (const int*)d_in[13]; const float* c3w0 = (const float*)d_in[14];
    const int*   c3i1  = (const int*)d_in[15]; const float* c3w1 = (const float*)d_in[16];
    const int*   c3i2  = (const int*)d_in[17]; const float* c3w2 = (const float*)d_in[18];
    const int*   fc1i  = (const int*)d_in[19]; const float* fc1w = (const float*)d_in[20];
    const int*   fc2i  = (const int*)d_in[21]; const float* fc2w = (const float*)d_in[22];
    const int*   fc3i  = (const int*)d_in[23]; const float* fc3w = (const float*)d_in[24];

    // ws: fcp1 @0 (20480*16=327680) | fcp2 @327680 (163840) | fcp3 @491520
    //     (81920) | convpack @573440 (208*224=46592) -> end 620032 B
    char* ws = (char*)d_ws;
    FcRec*  fcp1 = (FcRec*)ws;
    FcRec*  fcp2 = (FcRec*)(ws + 327680);
    FcRec*  fcp3 = (FcRec*)(ws + 491520);
    float4* cvp  = (float4*)(ws + 573440);

    setup_kernel<<<141, 256, 0, stream>>>(
        c1i0, c1i1, c1i2, c2i0, c2i1, c2i2, c3i0, c3i1, c3i2,
        c1w0, c1w1, c1w2, c2w0, c2w1, c2w2, c3w0, c3w1, c3w2,
        fc1i, fc1w, fc2i, fc2w, fc3i, fc3w,
        fcp1, fcp2, fcp3, cvp);

    fused_net<<<100, 1024, 0, stream>>>(
        x, fcp1, fcp2, fcp3, cvp, (float*)d_out);
}